// Round 1
// baseline (21599.629 us; speedup 1.0000x reference)
//
#include <hip/hip_runtime.h>

#define V_SZ 50000
#define E_SZ 256
#define H_SZ 512
#define B_SZ 16
#define S_SZ 400
#define T_SZ 100
#define UNK_TOK 1
#define NEGV -1e30f
#define NB 256

typedef unsigned short u16;
typedef unsigned int u32;
typedef __attribute__((ext_vector_type(8))) short sv8;
typedef __attribute__((ext_vector_type(4))) float f32x4;

__device__ __forceinline__ float bf2f(u16 u){ return __uint_as_float(((u32)u)<<16); }
__device__ __forceinline__ u16 f2bf(float x){
  u32 u = __float_as_uint(x);
  u32 r = (u + 0x7fffu + ((u>>16)&1u)) >> 16;
  return (u16)r;
}
__device__ __forceinline__ float wsum(float v){
  #pragma unroll
  for (int o=32;o;o>>=1) v += __shfl_xor(v,o);
  return v;
}
__device__ __forceinline__ float wmaxf(float v){
  #pragma unroll
  for (int o=32;o;o>>=1) v = fmaxf(v, __shfl_xor(v,o));
  return v;
}
__device__ __forceinline__ float ftanh(float x){
  float y = fminf(18.f, fmaxf(-18.f, 2.f*x));
  float e = __expf(y);
  return (e-1.f)/(e+1.f);
}
__device__ __forceinline__ float sigf(float x){ return 1.f/(1.f+__expf(-x)); }

// async global->LDS, 16B per lane, wave-uniform LDS base
__device__ __forceinline__ void gld16(const u16* g, u16* l){
  __builtin_amdgcn_global_load_lds((const __attribute__((address_space(1))) void*)g,
                                   (__attribute__((address_space(3))) void*)l, 16, 0, 0);
}

// ---------------- init ----------------
__global__ void k_init(u32* h_bf, int* flags, float* cov, float* loss_acc,
                       int* dflags, float* zeros){
  int idx = blockIdx.x*256 + threadIdx.x;
  if (idx < 16384) h_bf[idx] = 0u;          // encoder h bufs
  if (idx < 1024) flags[idx] = 0;           // encoder flags
  if (idx < B_SZ*S_SZ) cov[idx] = 0.f;
  if (idx < 64) loss_acc[idx] = 0.f;
  if (idx < NB*16) dflags[idx] = 0;         // decoder grid-barrier flags
  if (idx < 512) zeros[idx] = 0.f;
}

// ---------------- transposes / converts ----------------
__global__ void k_transpose(const float* __restrict__ in, float* __restrict__ out, int R, int C){
  __shared__ float t[32][33];
  int c0 = blockIdx.x*32, r0 = blockIdx.y*32;
  int x = threadIdx.x, y = threadIdx.y;
  for (int j=y;j<32;j+=8){
    int r=r0+j, c=c0+x;
    t[j][x] = (r<R && c<C) ? in[r*C+c] : 0.f;
  }
  __syncthreads();
  for (int j=y;j<32;j+=8){
    int oc = c0+j, orr = r0+x;
    if (oc<C && orr<R) out[oc*R+orr] = t[x][j];
  }
}
__global__ void k_f2bf(const float* __restrict__ in, u16* __restrict__ out, int n){
  for (int i = blockIdx.x*256 + threadIdx.x; i < n; i += gridDim.x*256) out[i] = f2bf(in[i]);
}
// W (Nt*16 rows x K cols) -> MFMA B-fragment-major bf16
__global__ void k_prep_frag(const float* __restrict__ W, u16* __restrict__ out, int Nt, int K32, int K){
  int idx = blockIdx.x*256 + threadIdx.x;
  if (idx >= Nt*K32*64) return;
  int lane = idx & 63; int kk = (idx>>6) % K32; int tile = idx / (K32*64);
  const float* src = W + (size_t)(tile*16 + (lane&15))*K + kk*32 + ((lane>>4)<<3);
  u16* dst = out + (size_t)idx*8;
  #pragma unroll
  for (int j=0;j<8;++j) dst[j] = f2bf(src[j]);
}

// ---------------- gathers ----------------
__global__ void k_gather_src(const int* __restrict__ src, const float* __restrict__ emb, float* __restrict__ xs){
  const int n = S_SZ*B_SZ*E_SZ;
  for (int idx = blockIdx.x*blockDim.x + threadIdx.x; idx < n; idx += gridDim.x*blockDim.x){
    int e = idx & 255; int sb = idx >> 8; int b = sb & 15; int s = sb >> 4;
    int tok = src[b*S_SZ + s]; if (tok >= V_SZ) tok = UNK_TOK;
    xs[idx] = emb[tok*E_SZ + e];
  }
}
__global__ void k_gather_dec(const int* __restrict__ tgt, const float* __restrict__ emb, float* __restrict__ dx){
  const int n = (T_SZ-1)*B_SZ*E_SZ;
  for (int idx = blockIdx.x*blockDim.x + threadIdx.x; idx < n; idx += gridDim.x*blockDim.x){
    int e = idx & 255; int tb = idx >> 8; int b = tb & 15; int t = tb >> 4;
    int tok = tgt[b*T_SZ + t]; if (tok >= V_SZ) tok = UNK_TOK;
    dx[idx] = emb[tok*E_SZ + e];
  }
}
__global__ void k_gxscore(const float* __restrict__ dx, const float* __restrict__ gW, float* __restrict__ gx){
  int i = blockIdx.x*blockDim.x + threadIdx.x;
  if (i < (T_SZ-1)*B_SZ){
    const float* x = dx + i*E_SZ;
    const float* g = gW + 1024;
    float a = 0.f;
    for (int e=0;e<E_SZ;++e) a += x[e]*g[e];
    gx[i] = a;
  }
}

// ---------------- generic GEMM: C(M,N) = A(M,K) @ WT(K,N) + bias(N) ----------------
__global__ __launch_bounds__(256) void k_gemm(const float* __restrict__ A, const float* __restrict__ WT,
                       const float* __restrict__ bias, float* __restrict__ C,
                       int M, int N, int K){
  __shared__ float As[32][36];
  int n = blockIdx.x*64 + (threadIdx.x & 63);
  int wv = threadIdx.x >> 6;
  int m0 = blockIdx.y*32;
  float acc[8];
  #pragma unroll
  for (int j=0;j<8;++j) acc[j]=0.f;
  for (int k0=0;k0<K;k0+=32){
    for (int e=threadIdx.x; e<1024; e+=256){
      int r = e>>5, c = e&31;
      int m = m0 + r;
      As[c][r] = (m<M)? A[m*K + k0 + c] : 0.f;
    }
    __syncthreads();
    #pragma unroll 8
    for (int k=0;k<32;++k){
      float w = WT[(k0+k)*N + n];
      const float* as = &As[k][wv*8];
      #pragma unroll
      for (int j=0;j<8;++j) acc[j] += as[j]*w;
    }
    __syncthreads();
  }
  float bv = bias[n];
  #pragma unroll
  for (int j=0;j<8;++j){
    int m = m0 + wv*8 + j;
    if (m<M) C[m*N + n] = acc[j] + bv;
  }
}

// ---------------- persistent bidirectional GRU encoder (flag-sync) ----------------
__global__ __launch_bounds__(64) void k_enc_persist(
    const float* __restrict__ gi_f, const float* __restrict__ gi_b,
    const u16* __restrict__ Wbf_f, const u16* __restrict__ Wbf_b,
    const float* __restrict__ bhh_f, const float* __restrict__ bhh_b,
    float* __restrict__ enc_out, float* __restrict__ enc_hid,
    u16* __restrict__ h_bf, int* __restrict__ flags){
  __shared__ u16 wl[48*512];   // 48KB
  int lane = threadIdx.x;
  int d = blockIdx.x >> 5, slice = blockIdx.x & 31;
  int h0 = slice*16;
  const u16* Wb = d ? Wbf_b : Wbf_f;
  const float* gi = d ? gi_b : gi_f;
  const float* bhh = d ? bhh_b : bhh_f;
  int hl = h0 + (lane & 15);
  int quad = lane >> 4;
  int* myflag = flags + (d*32 + slice)*16;
  int* pollp  = flags + (d*32 + (lane & 31))*16;

  #pragma unroll 4
  for (int i=0;i<48;++i){
    int gg = i>>4, kk = i&15;
    const u16* src = Wb + ((size_t)(gg*512 + hl))*512 + kk*32 + quad*8;
    *(sv8*)&wl[i*512 + lane*8] = *(const sv8*)src;
  }
  __syncthreads();

  float b0 = bhh[hl], b1 = bhh[512+hl], b2 = bhh[1024+hl];
  float hold[4] = {0.f,0.f,0.f,0.f};

  #pragma unroll 1
  for (int t=0;t<S_SZ;++t){
    int pos = d ? (S_SZ-1-t) : t;
    const float* gp = gi + ((size_t)pos*16)*1536 + hl;
    float giv[12];
    #pragma unroll
    for (int gg=0;gg<3;++gg)
      #pragma unroll
      for (int r=0;r<4;++r)
        giv[gg*4+r] = gp[(quad*4 + r)*1536 + gg*512];

    if (t > 0){
      while (true){
        int v = __hip_atomic_load(pollp, __ATOMIC_RELAXED, __HIP_MEMORY_SCOPE_AGENT);
        unsigned long long m = __ballot(v >= t);
        if (m == ~0ull) break;
        __builtin_amdgcn_s_sleep(1);
      }
      __threadfence();
    }

    const u16* hb = h_bf + ((size_t)(t&1)*2 + d)*8192 + (lane&15)*512 + quad*8;
    f32x4 a0={0.f,0.f,0.f,0.f}, a1={0.f,0.f,0.f,0.f}, a2={0.f,0.f,0.f,0.f};
    #pragma unroll
    for (int kk=0;kk<16;++kk){
      sv8 a = *(const sv8*)(hb + kk*32);
      a0 = __builtin_amdgcn_mfma_f32_16x16x32_bf16(a, *(const sv8*)&wl[(kk)*512 + lane*8], a0, 0,0,0);
      a1 = __builtin_amdgcn_mfma_f32_16x16x32_bf16(a, *(const sv8*)&wl[(16+kk)*512 + lane*8], a1, 0,0,0);
      a2 = __builtin_amdgcn_mfma_f32_16x16x32_bf16(a, *(const sv8*)&wl[(32+kk)*512 + lane*8], a2, 0,0,0);
    }
    u16* hw = h_bf + ((size_t)((t+1)&1)*2 + d)*8192;
    #pragma unroll
    for (int r=0;r<4;++r){
      int b = quad*4 + r;
      float rg = sigf(giv[r]   + a0[r] + b0);
      float zg = sigf(giv[4+r] + a1[r] + b1);
      float ng = ftanh(giv[8+r] + rg*(a2[r] + b2));
      float hv = (1.f-zg)*ng + zg*hold[r];
      hold[r] = hv;
      enc_out[((size_t)b*S_SZ + pos)*1024 + d*512 + hl] = hv;
      hw[b*512 + hl] = f2bf(hv);
      if (t == S_SZ-1) enc_hid[b*1024 + d*512 + hl] = hv;
    }
    __threadfence();
    if (lane == 0)
      __hip_atomic_store(myflag, t+1, __ATOMIC_RELEASE, __HIP_MEMORY_SCOPE_AGENT);
  }
}

// ---------------- ctx_red = ctx @ rW.T + rb ; writes h_cur (f32) + u_bf lower half ----------------
__global__ __launch_bounds__(256) void k_ctxred(const float* __restrict__ ctx, const float* __restrict__ rWT,
    const float* __restrict__ rb, float* __restrict__ h_cur, u16* __restrict__ u_bf){
  __shared__ float As[64][17];
  int lane = threadIdx.x & 63, wv = threadIdx.x >> 6;
  int n = blockIdx.x*64 + lane;
  float acc[4] = {0.f,0.f,0.f,0.f};
  for (int k0=0;k0<1024;k0+=64){
    for (int e=threadIdx.x; e<1024; e+=256){
      int r = e & 15, c = e >> 4;
      As[c][r] = ctx[r*1024 + k0 + c];
    }
    __syncthreads();
    #pragma unroll 8
    for (int k=0;k<64;++k){
      float w = rWT[(k0+k)*512 + n];
      #pragma unroll
      for (int j=0;j<4;++j) acc[j] += As[k][wv*4+j]*w;
    }
    __syncthreads();
  }
  float bv = rb[n];
  #pragma unroll
  for (int j=0;j<4;++j){
    int m = wv*4+j;
    float val = acc[j] + bv;
    h_cur[m*512 + n] = val;
    u_bf[m*1024 + n] = f2bf(val);
  }
}

// ---------------- grid barrier (flag-per-block, agent scope) ----------------
__device__ __forceinline__ void gbar(int* __restrict__ flg, int bi){
  __syncthreads();
  if (threadIdx.x == 0){
    __threadfence();
    __hip_atomic_store(flg + blockIdx.x*16, bi, __ATOMIC_RELEASE, __HIP_MEMORY_SCOPE_AGENT);
  }
  if (threadIdx.x < 64){
    int i0 = threadIdx.x*4;
    for (;;){
      int v0 = __hip_atomic_load(flg + (i0+0)*16, __ATOMIC_RELAXED, __HIP_MEMORY_SCOPE_AGENT);
      int v1 = __hip_atomic_load(flg + (i0+1)*16, __ATOMIC_RELAXED, __HIP_MEMORY_SCOPE_AGENT);
      int v2 = __hip_atomic_load(flg + (i0+2)*16, __ATOMIC_RELAXED, __HIP_MEMORY_SCOPE_AGENT);
      int v3 = __hip_atomic_load(flg + (i0+3)*16, __ATOMIC_RELAXED, __HIP_MEMORY_SCOPE_AGENT);
      int mn = min(min(v0,v1),min(v2,v3));
      if (__ballot(mn >= bi) == ~0ull) break;
      __builtin_amdgcn_s_sleep(1);
    }
    __threadfence();
  }
  __syncthreads();
}

// ---------------- fused persistent decoder: all 99 steps, 7 grid barriers/step ----------------
__global__ __launch_bounds__(256,2) void k_decoder(
    const float* __restrict__ dec_gi, u16* __restrict__ u_bf,
    const u16* __restrict__ dfrag, const u16* __restrict__ sfrag,
    const float* __restrict__ dbhh, const float* __restrict__ abs_,
    const float* __restrict__ WhEnc, const float* __restrict__ aWc,
    const float* __restrict__ abc, const float* __restrict__ aV,
    const float* __restrict__ abv, const float* __restrict__ mask,
    const float* __restrict__ encR, const float* __restrict__ rb,
    const u16* __restrict__ fwB, const float* __restrict__ fb,
    const int* __restrict__ src_vecs, const int* __restrict__ tgt_vecs,
    const float* __restrict__ gW, const float* __restrict__ gb,
    const float* __restrict__ gx,
    float* __restrict__ hdec2, float* __restrict__ s_part,
    float* __restrict__ e_buf, float* __restrict__ attn,
    float* __restrict__ cov, float* __restrict__ ctxp,
    u16* __restrict__ aFragLo, float* __restrict__ h_cur,
    float* __restrict__ se_wave, float* __restrict__ logit_tgt,
    float* __restrict__ covloss, float* __restrict__ loss_acc,
    int* __restrict__ flg){
  int tid = threadIdx.x;
  int lane = tid & 63;
  int wv = tid >> 6;
  int blk = blockIdx.x;
  int gw = blk*4 + wv;
  int quad = lane >> 4;
  int bi = 0;
  float loss_local = 0.f;
  __shared__ __align__(16) char smem[49152];   // 48KB: G uses 32KB a_lds + 16KB b-staging

  // ---- loss phase (per-b block; runs overlapped with next step's GRU phase) ----
  auto phaseH = [&](int tt){
    int b = blk;
    float a1 = 0.f, a2v = 0.f, a3 = 0.f;
    const float* sw = se_wave + b*1024;
    #pragma unroll
    for (int i=0;i<4;++i) a1 += sw[tid + i*256];
    {
      const float* hc = h_cur + b*512;
      const float* hd = hdec2 + (size_t)(tt&1)*8192 + b*512;
      a2v = hc[tid]*gW[tid] + hd[tid]*gW[512+tid]
          + hc[256+tid]*gW[256+tid] + hd[256+tid]*gW[768+tid];
    }
    int tg = tgt_vecs[b*T_SZ + tt + 1];
    if (src_vecs[b*S_SZ + tid] == tg) a3 += attn[b*S_SZ + tid];
    if (tid < 144 && src_vecs[b*S_SZ + 256 + tid] == tg) a3 += attn[b*S_SZ + 256 + tid];
    a1 = wsum(a1); a2v = wsum(a2v); a3 = wsum(a3);
    float* red = (float*)smem;
    if (lane == 0){ red[wv] = a1; red[4+wv] = a2v; red[8+wv] = a3; }
    __syncthreads();
    if (tid == 0){
      float sume = red[0]+red[1]+red[2]+red[3];
      float dd   = red[4]+red[5]+red[6]+red[7];
      float ptr  = red[8]+red[9]+red[10]+red[11];
      float sc = dd + gx[tt*16 + b] + gb[0];
      float pg = fminf(0.999f, fmaxf(0.001f, sigf(sc)));
      float tp = pg * (__expf(logit_tgt[b]) / sume) + (1.f-pg)*ptr;
      if (tg != 0) loss_local += -logf(tp + 1e-9f) + covloss[b];
    }
    __syncthreads();
  };

  for (int t = 0; t < T_SZ-1; ++t){
    // ===== A: decoder GRU cell (blocks 16..23)  ||  H(t-1) on blocks 0..15 =====
    if (blk >= 16 && blk < 24){
      int slice = (blk-16)*4 + wv;
      int h = slice*16 + (lane & 15);
      const u16* ap = u_bf + (lane&15)*1024 + quad*8;
      f32x4 a0={0.f,0.f,0.f,0.f}, a1=a0, a2=a0;
      #pragma unroll
      for (int kk=0;kk<16;++kk){
        sv8 a = *(const sv8*)(ap + kk*32);
        a0 = __builtin_amdgcn_mfma_f32_16x16x32_bf16(a, *(const sv8*)(dfrag + ((size_t)(0*32+slice)*16 + kk)*512 + lane*8), a0, 0,0,0);
        a1 = __builtin_amdgcn_mfma_f32_16x16x32_bf16(a, *(const sv8*)(dfrag + ((size_t)(1*32+slice)*16 + kk)*512 + lane*8), a1, 0,0,0);
        a2 = __builtin_amdgcn_mfma_f32_16x16x32_bf16(a, *(const sv8*)(dfrag + ((size_t)(2*32+slice)*16 + kk)*512 + lane*8), a2, 0,0,0);
      }
      float b0 = dbhh[h], b1 = dbhh[512+h], b2 = dbhh[1024+h];
      const float* gi = dec_gi + (size_t)t*16*1536 + h;
      float* hd = hdec2 + (size_t)(t&1)*8192;
      #pragma unroll
      for (int r=0;r<4;++r){
        int b = quad*4 + r;
        const float* gp = gi + b*1536;
        float hlv = bf2f(u_bf[b*1024 + h]);
        float rg = sigf(gp[0]    + a0[r] + b0);
        float zg = sigf(gp[512]  + a1[r] + b1);
        float ng = ftanh(gp[1024] + rg*(a2[r] + b2));
        float hv = (1.f-zg)*ng + zg*hlv;
        hd[b*512 + h] = hv;
        u_bf[b*1024 + 512 + h] = f2bf(hv);
      }
    } else if (blk < 16 && t > 0){
      phaseH(t-1);
    }
    gbar(flg, ++bi);

    // ===== B: s_part = hdec @ aWs.T + abs_ (blocks 16..23) =====
    if (blk >= 16 && blk < 24){
      int slice = (blk-16)*4 + wv;
      const u16* ap = u_bf + (lane&15)*1024 + 512 + quad*8;
      const u16* bp = sfrag + (size_t)slice*16*512 + lane*8;
      f32x4 acc={0.f,0.f,0.f,0.f};
      #pragma unroll
      for (int kk=0;kk<16;++kk){
        sv8 a = *(const sv8*)(ap + kk*32);
        acc = __builtin_amdgcn_mfma_f32_16x16x32_bf16(a, *(const sv8*)(bp + kk*512), acc, 0,0,0);
      }
      int h = slice*16 + (lane & 15);
      float bv = abs_[h];
      #pragma unroll
      for (int r=0;r<4;++r) s_part[(quad*4+r)*512 + h] = acc[r] + bv;
    }
    gbar(flg, ++bi);

    // ===== C: attention scores (all blocks: block = b*16 + s-chunk) =====
    {
      float* sp  = (float*)smem;
      float* wcs = sp + 512;
      float* abS = sp + 1024;
      float* avS = sp + 1536;
      int b = blk >> 4, chunk = blk & 15;
      for (int i = tid; i < 512; i += 256){
        sp[i]  = s_part[b*512 + i];
        wcs[i] = aWc[i];
        abS[i] = abc[i];
        avS[i] = aV[i];
      }
      __syncthreads();
      float abv0 = abv[0];
      int s0 = chunk*25;
      for (int s = s0 + wv; s < s0 + 25; s += 4){
        float cv = cov[b*S_SZ + s];
        const float* wh = WhEnc + (size_t)(b*S_SZ + s)*512;
        float a = 0.f;
        #pragma unroll
        for (int j=0;j<8;++j){
          int h = j*64 + lane;
          a += ftanh(wh[h] + sp[h] + cv*wcs[h] + abS[h]) * avS[h];
        }
        a = wsum(a);
        if (lane == 0){
          float e = a + abv0;
          if (!(mask[b*S_SZ + s] > 0.f)) e = NEGV;
          e_buf[b*S_SZ + s] = e;
        }
      }
    }
    gbar(flg, ++bi);

    // ===== D: softmax + coverage update + covloss (blocks 0..15) =====
    if (blk < 16){
      int b = blk;
      float* red = (float*)smem;
      float e0 = e_buf[b*S_SZ + tid];
      float e1 = (tid < 144) ? e_buf[b*S_SZ + 256 + tid] : NEGV;
      float m = wmaxf(fmaxf(e0, e1));
      if (lane == 0) red[wv] = m;
      __syncthreads();
      float mx = fmaxf(fmaxf(red[0],red[1]), fmaxf(red[2],red[3]));
      float p0 = __expf(e0 - mx);
      float p1 = (tid < 144) ? __expf(e1 - mx) : 0.f;
      float sm = wsum(p0 + p1);
      if (lane == 0) red[4+wv] = sm;
      __syncthreads();
      float inv = 1.f/(red[4]+red[5]+red[6]+red[7]);
      float ml;
      {
        float a0v = p0*inv;
        attn[b*S_SZ + tid] = a0v;
        float cn = cov[b*S_SZ + tid] + a0v;
        cov[b*S_SZ + tid] = cn;
        ml = fminf(a0v, cn);
      }
      if (tid < 144){
        float a1v = p1*inv;
        attn[b*S_SZ + 256 + tid] = a1v;
        float cn = cov[b*S_SZ + 256 + tid] + a1v;
        cov[b*S_SZ + 256 + tid] = cn;
        ml += fminf(a1v, cn);
      }
      float cs = wsum(ml);
      if (lane == 0) red[8+wv] = cs;
      __syncthreads();
      if (tid == 0) covloss[b] = red[8]+red[9]+red[10]+red[11];
    }
    gbar(flg, ++bi);

    // ===== E: ctx_red partials = attn @ encR (1024 wave-tasks: b x n64 x s-eighth) =====
    {
      int b = gw >> 6, rem = gw & 63;
      int n0 = (rem >> 3) * 64;
      int q = rem & 7;
      const float* er = encR + ((size_t)(b*S_SZ) + q*50)*512 + n0 + lane;
      const float* at = attn + b*S_SZ + q*50;
      float acc = 0.f;
      #pragma unroll 5
      for (int s=0;s<50;++s) acc += at[s] * er[(size_t)s*512];
      ctxp[(q*16 + b)*512 + n0 + lane] = acc;
    }
    gbar(flg, ++bi);

    // ===== E2: combine partials -> ctx_red: aFragLo (bf16 frags) + u_bf lower + h_cur =====
    if (blk < 4){
      int f = blk*256 + tid;            // frag id in lower K-half (kk<16)
      int kk = f >> 6, l = f & 63, r = l & 15;
      int c8 = ((l >> 4) << 3) + kk*32;
      float v[8];
      #pragma unroll
      for (int j=0;j<8;++j) v[j] = rb[c8+j];
      #pragma unroll
      for (int q=0;q<8;++q){
        const float* pp = ctxp + q*8192 + r*512 + c8;
        #pragma unroll
        for (int j=0;j<8;++j) v[j] += pp[j];
      }
      sv8 fr;
      #pragma unroll
      for (int j=0;j<8;++j) fr[j] = (short)f2bf(v[j]);
      *(sv8*)&aFragLo[(size_t)f*8] = fr;
      *(sv8*)&u_bf[r*1024 + c8] = fr;
      f32x4 v0 = {v[0],v[1],v[2],v[3]};
      f32x4 v1 = {v[4],v[5],v[6],v[7]};
      *(f32x4*)&h_cur[r*512 + c8] = v0;
      *(f32x4*)&h_cur[r*512 + c8 + 4] = v1;
    }
    gbar(flg, ++bi);

    // ===== G: vocab logits via MFMA, LDS double-buffered fwB staging =====
    {
      u16* a_lds = (u16*)smem;                       // 2048 frags x 16B = 32KB
      // build A fragments (ctx_red half from aFragLo, hdec half from u_bf upper)
      for (int f = tid; f < 2048; f += 256){
        sv8 fr;
        if (f < 1024){
          fr = *(const sv8*)&aFragLo[(size_t)f*8];
        } else {
          int kk = f >> 6, l = f & 63, r = l & 15;
          int c8 = ((l >> 4) << 3) + kk*32;          // >= 512
          fr = *(const sv8*)&u_bf[r*1024 + c8];
        }
        *(sv8*)&a_lds[(size_t)f*8] = fr;
      }
      __syncthreads();

      u16* mybuf = (u16*)(smem + 32768) + wv*2048;   // 2 bufs x 1024 u16 per wave
      int nT = (gw < 53) ? 4 : 3;                    // 3125 tiles over 1024 waves
      int nC = nT * 16;                              // chunks of 2 kk (2KB)
      int tgtv[4];
      #pragma unroll
      for (int r=0;r<4;++r) tgtv[r] = tgt_vecs[(quad*4 + r)*T_SZ + t + 1];
      float es[4] = {0.f,0.f,0.f,0.f};
      f32x4 acc = {0.f,0.f,0.f,0.f};

      auto STAGE = [&](int c){
        int tl = gw + ((c >> 4) << 10);
        const u16* src = fwB + (size_t)tl*16384 + (size_t)(c & 15)*1024 + lane*8;
        u16* dst = mybuf + (c & 1)*1024;
        gld16(src, dst);
        gld16(src + 512, dst + 512);
      };
      STAGE(0); STAGE(1);
      #pragma unroll 1
      for (int c = 0; c < nC; ++c){
        if (c + 1 < nC) { asm volatile("s_waitcnt vmcnt(2)" ::: "memory"); }
        else            { asm volatile("s_waitcnt vmcnt(0)" ::: "memory"); }
        const u16* bp = mybuf + (c & 1)*1024 + lane*8;
        int kk0 = (c & 15)*2;
        #pragma unroll
        for (int j=0;j<2;++j){
          sv8 af  = *(const sv8*)&a_lds[(size_t)(kk0+j)*512 + lane*8];
          sv8 bfr = *(const sv8*)&bp[j*512];
          acc = __builtin_amdgcn_mfma_f32_16x16x32_bf16(af, bfr, acc, 0,0,0);
        }
        if ((c & 15) == 15){
          int tl = gw + ((c >> 4) << 10);
          int v = tl*16 + (lane & 15);
          float fbv = fb[v];
          #pragma unroll
          for (int r=0;r<4;++r){
            float lg = acc[r] + fbv;
            if (v == tgtv[r]) logit_tgt[quad*4 + r] = lg;
            es[r] += __expf(lg);
          }
          acc[0]=0.f; acc[1]=0.f; acc[2]=0.f; acc[3]=0.f;
        }
        asm volatile("" ::: "memory");
        if (c + 2 < nC) STAGE(c + 2);
      }
      #pragma unroll
      for (int o=1;o<16;o<<=1){
        #pragma unroll
        for (int r=0;r<4;++r) es[r] += __shfl_xor(es[r], o);
      }
      if ((lane & 15) == 0){
        #pragma unroll
        for (int r=0;r<4;++r) se_wave[(size_t)(quad*4 + r)*1024 + gw] = es[r];
      }
    }
    gbar(flg, ++bi);
  }

  // final loss phase for t = 98
  if (blk < 16){
    phaseH(T_SZ-2);
    if (tid == 0) loss_acc[blk] = loss_local;
  }
}

// ---------------- output ----------------
__global__ void k_out(const float* __restrict__ loss_acc, const int* __restrict__ tgt_vecs, float* __restrict__ out){
  __shared__ float s[16];
  int tid = threadIdx.x;
  if (tid < 16){
    int c = 0;
    for (int t=0;t<T_SZ;++t) c += (tgt_vecs[tid*T_SZ + t] != 0) ? 1 : 0;
    s[tid] = loss_acc[tid] / (float)(c - 1);
  }
  __syncthreads();
  if (tid == 0){
    float a = 0.f;
    for (int b=0;b<16;++b) a += s[b];
    out[0] = a / 16.f;
  }
}

extern "C" void kernel_launch(void* const* d_in, const int* in_sizes, int n_in,
                              void* d_out, int out_size, void* d_ws, size_t ws_size,
                              hipStream_t stream){
  (void)in_sizes; (void)n_in; (void)out_size; (void)ws_size;
  const int*   src_vecs = (const int*)d_in[0];
  const float* src_mask = (const float*)d_in[1];
  const int*   tgt_vecs = (const int*)d_in[2];
  const float* enc_embed= (const float*)d_in[4];
  const float* dec_embed= (const float*)d_in[5];
  const float* eWih_f = (const float*)d_in[6];
  const float* eWhh_f = (const float*)d_in[7];
  const float* ebih_f = (const float*)d_in[8];
  const float* ebhh_f = (const float*)d_in[9];
  const float* eWih_b = (const float*)d_in[10];
  const float* eWhh_b = (const float*)d_in[11];
  const float* ebih_b = (const float*)d_in[12];
  const float* ebhh_b = (const float*)d_in[13];
  const float* dWih = (const float*)d_in[14];
  const float* dWhh = (const float*)d_in[15];
  const float* dbih = (const float*)d_in[16];
  const float* dbhh = (const float*)d_in[17];
  const float* aWh  = (const float*)d_in[18];
  const float* abh  = (const float*)d_in[19];
  const float* aWs  = (const float*)d_in[20];
  const float* abs_ = (const float*)d_in[21];
  const float* aWc  = (const float*)d_in[22];
  const float* abc  = (const float*)d_in[23];
  const float* aV   = (const float*)d_in[24];
  const float* abv  = (const float*)d_in[25];
  const float* rW   = (const float*)d_in[26];
  const float* rb   = (const float*)d_in[27];
  const float* gW   = (const float*)d_in[28];
  const float* gb   = (const float*)d_in[29];
  const float* fW   = (const float*)d_in[30];
  const float* fb   = (const float*)d_in[31];
  float* out = (float*)d_out;

  char* p = (char*)d_ws;
  auto alloc = [&](size_t n)->char*{ char* r = p; p += (n + 255) & ~(size_t)255; return r; };
  float* xs      = (float*)alloc((size_t)S_SZ*B_SZ*E_SZ*4);
  float* gi_f    = (float*)alloc((size_t)S_SZ*B_SZ*1536*4);
  float* gi_b    = (float*)alloc((size_t)S_SZ*B_SZ*1536*4);
  float* enc_out = (float*)alloc((size_t)B_SZ*S_SZ*1024*4);
  float* WhEnc   = (float*)alloc((size_t)B_SZ*S_SZ*512*4);
  float* dec_x   = (float*)alloc((size_t)(T_SZ-1)*B_SZ*E_SZ*4);
  float* dec_gi  = (float*)alloc((size_t)(T_SZ-1)*B_SZ*1536*4);
  float* gx      = (float*)alloc((size_t)(T_SZ-1)*B_SZ*4);
  float* eWihT_f = (float*)alloc((size_t)256*1536*4);
  float* eWihT_b = (float*)alloc((size_t)256*1536*4);
  float* dWihT   = (float*)alloc((size_t)256*1536*4);
  float* aWhT    = (float*)alloc((size_t)1024*512*4);
  float* rWT     = (float*)alloc((size_t)1024*512*4);
  u16* Wbf_f     = (u16*)alloc((size_t)1536*512*2);
  u16* Wbf_b     = (u16*)alloc((size_t)1536*512*2);
  u16* dfrag     = (u16*)alloc((size_t)96*16*512*2);
  u16* sfrag     = (u16*)alloc((size_t)32*16*512*2);
  u16* fwB       = (u16*)alloc((size_t)3125*16384*2);
  u16* h_bf      = (u16*)alloc((size_t)2*2*16*512*2);
  u16* u_bf      = (u16*)alloc((size_t)16*1024*2);
  int* flags     = (int*)alloc(64*16*4);
  float* enc_hid = (float*)alloc((size_t)B_SZ*1024*4);
  float* h_cur   = (float*)alloc((size_t)B_SZ*H_SZ*4);
  float* s_part  = (float*)alloc((size_t)B_SZ*H_SZ*4);
  float* e_buf   = (float*)alloc((size_t)B_SZ*S_SZ*4);
  float* attn    = (float*)alloc((size_t)B_SZ*S_SZ*4);
  float* cov     = (float*)alloc((size_t)B_SZ*S_SZ*4);
  float* logit_tgt = (float*)alloc(64*4);
  float* covloss = (float*)alloc(64*4);
  float* loss_acc= (float*)alloc(64*4);
  // new buffers for fused decoder
  float* encR    = (float*)alloc((size_t)B_SZ*S_SZ*512*4);     // enc_out @ rW.T
  float* ctxp    = (float*)alloc((size_t)8*16*512*4);          // ctx_red partials
  u16* aFragLo   = (u16*)alloc((size_t)1024*8*2);              // ctx_red MFMA A-frags
  float* se_wave = (float*)alloc((size_t)16*1024*4);           // per-wave exp sums
  float* hdec2   = (float*)alloc((size_t)2*B_SZ*H_SZ*4);       // double-buffered hdec
  int* dflags    = (int*)alloc((size_t)NB*16*4);               // decoder grid barrier
  float* zeros512= (float*)alloc(512*4);

  dim3 tb(32,8);
  k_init<<<128,256,0,stream>>>((u32*)h_bf, flags, cov, loss_acc, dflags, zeros512);
  k_transpose<<<dim3(8,48),tb,0,stream>>>(eWih_f, eWihT_f, 1536, 256);
  k_transpose<<<dim3(8,48),tb,0,stream>>>(eWih_b, eWihT_b, 1536, 256);
  k_transpose<<<dim3(8,48),tb,0,stream>>>(dWih, dWihT, 1536, 256);
  k_transpose<<<dim3(32,16),tb,0,stream>>>(aWh, aWhT, 512, 1024);
  k_transpose<<<dim3(32,16),tb,0,stream>>>(rW, rWT, 512, 1024);
  k_f2bf<<<3072,256,0,stream>>>(eWhh_f, Wbf_f, 1536*512);
  k_f2bf<<<3072,256,0,stream>>>(eWhh_b, Wbf_b, 1536*512);
  k_prep_frag<<<384,256,0,stream>>>(dWhh, dfrag, 96, 16, 512);
  k_prep_frag<<<128,256,0,stream>>>(aWs, sfrag, 32, 16, 512);
  k_prep_frag<<<25000,256,0,stream>>>(fW, fwB, 3125, 32, 1024);
  k_gather_src<<<1024,256,0,stream>>>(src_vecs, enc_embed, xs);
  k_gather_dec<<<512,256,0,stream>>>(tgt_vecs, dec_embed, dec_x);
  k_gxscore<<<7,256,0,stream>>>(dec_x, gW, gx);
  k_gemm<<<dim3(24,200),256,0,stream>>>(xs, eWihT_f, ebih_f, gi_f, 6400,1536,256);
  k_gemm<<<dim3(24,200),256,0,stream>>>(xs, eWihT_b, ebih_b, gi_b, 6400,1536,256);
  k_gemm<<<dim3(24,50),256,0,stream>>>(dec_x, dWihT, dbih, dec_gi, 1584,1536,256);

  k_enc_persist<<<64,64,0,stream>>>(gi_f, gi_b, Wbf_f, Wbf_b, ebhh_f, ebhh_b,
                                    enc_out, enc_hid, h_bf, flags);

  // h_dec0 = enc_hid @ rW.T + rb  (seeds u_bf lower half for step 0)
  k_ctxred<<<8,256,0,stream>>>(enc_hid, rWT, rb, h_cur, u_bf);
  k_gemm<<<dim3(8,200),256,0,stream>>>(enc_out, aWhT, abh, WhEnc, 6400,512,1024);
  // encR = enc_out @ rW.T (no bias; rb folded in at combine) — enables ctx/ctx_red fusion
  k_gemm<<<dim3(8,200),256,0,stream>>>(enc_out, rWT, zeros512, encR, 6400,512,1024);

  k_decoder<<<NB,256,0,stream>>>(dec_gi, u_bf, dfrag, sfrag, dbhh, abs_,
                                 WhEnc, aWc, abc, aV, abv, src_mask,
                                 encR, rb, fwB, fb, src_vecs, tgt_vecs,
                                 gW, gb, gx,
                                 hdec2, s_part, e_buf, attn, cov, ctxp,
                                 aFragLo, h_cur, se_wave, logit_tgt, covloss,
                                 loss_acc, dflags);

  k_out<<<1,64,0,stream>>>(loss_acc, tgt_vecs, out);
}

// Round 2
// 21553.618 us; speedup vs baseline: 1.0021x; 1.0021x over previous
//
#include <hip/hip_runtime.h>

#define V_SZ 50000
#define E_SZ 256
#define H_SZ 512
#define B_SZ 16
#define S_SZ 400
#define T_SZ 100
#define UNK_TOK 1
#define NEGV -1e30f
#define NB 256

// decoder block roles
#define SGB 64      // chain blocks 0..63
#define LOSS0 64    // loss blocks 64..79
#define NLOSS 16
#define GG0 80      // vocab blocks 80..255
#define NGG 176
#define NGW 704     // vocab waves

// flag slot offsets (slot = 16 ints = 64B)
#define FA 0
#define FB 8
#define FC 16
#define FD 80
#define FE 96
#define FE2 160
#define FG 164
#define FH 340
// total 356 slots (alloc 512)

typedef unsigned short u16;
typedef unsigned int u32;
typedef __attribute__((ext_vector_type(8))) short sv8;
typedef __attribute__((ext_vector_type(4))) float f32x4;

__device__ __forceinline__ float bf2f(u16 u){ return __uint_as_float(((u32)u)<<16); }
__device__ __forceinline__ u16 f2bf(float x){
  u32 u = __float_as_uint(x);
  u32 r = (u + 0x7fffu + ((u>>16)&1u)) >> 16;
  return (u16)r;
}
__device__ __forceinline__ float wsum(float v){
  #pragma unroll
  for (int o=32;o;o>>=1) v += __shfl_xor(v,o);
  return v;
}
__device__ __forceinline__ float wmaxf(float v){
  #pragma unroll
  for (int o=32;o;o>>=1) v = fmaxf(v, __shfl_xor(v,o));
  return v;
}
__device__ __forceinline__ float ftanh(float x){
  float y = fminf(18.f, fmaxf(-18.f, 2.f*x));
  float e = __expf(y);
  return (e-1.f)/(e+1.f);
}
__device__ __forceinline__ float sigf(float x){ return 1.f/(1.f+__expf(-x)); }

__device__ __forceinline__ void gld16(const u16* g, u16* l){
  __builtin_amdgcn_global_load_lds((const __attribute__((address_space(1))) void*)g,
                                   (__attribute__((address_space(3))) void*)l, 16, 0, 0);
}

// wave0 polls n flag slots (stride 16 ints) for >= tgt; whole block fenced after.
__device__ __forceinline__ void wait_ge(const int* f, int n, int tgt){
  if (threadIdx.x < 64){
    for(;;){
      int mn = 0x7fffffff;
      for (int i = threadIdx.x; i < n; i += 64)
        mn = min(mn, __hip_atomic_load(f + i*16, __ATOMIC_RELAXED, __HIP_MEMORY_SCOPE_AGENT));
      if (__ballot(mn >= tgt) == ~0ull) break;
      __builtin_amdgcn_s_sleep(2);
    }
  }
  __syncthreads();
  __threadfence();
}
__device__ __forceinline__ void post(int* slot, int v){
  __syncthreads();
  if (threadIdx.x == 0){
    __threadfence();
    __hip_atomic_store(slot, v, __ATOMIC_RELEASE, __HIP_MEMORY_SCOPE_AGENT);
  }
}

// ---------------- init ----------------
__global__ void k_init(u32* h_bf, int* flags, float* cov, float* loss_acc,
                       int* dflags, float* zeros){
  int idx = blockIdx.x*256 + threadIdx.x;
  if (idx < 16384) h_bf[idx] = 0u;
  if (idx < 1024) flags[idx] = 0;
  if (idx < B_SZ*S_SZ) cov[idx] = 0.f;
  if (idx < 64) loss_acc[idx] = 0.f;
  if (idx < 8192) dflags[idx] = 0;
  if (idx < 512) zeros[idx] = 0.f;
}

// ---------------- transposes / converts ----------------
__global__ void k_transpose(const float* __restrict__ in, float* __restrict__ out, int R, int C){
  __shared__ float t[32][33];
  int c0 = blockIdx.x*32, r0 = blockIdx.y*32;
  int x = threadIdx.x, y = threadIdx.y;
  for (int j=y;j<32;j+=8){
    int r=r0+j, c=c0+x;
    t[j][x] = (r<R && c<C) ? in[r*C+c] : 0.f;
  }
  __syncthreads();
  for (int j=y;j<32;j+=8){
    int oc = c0+j, orr = r0+x;
    if (oc<C && orr<R) out[oc*R+orr] = t[x][j];
  }
}
__global__ void k_f2bf(const float* __restrict__ in, u16* __restrict__ out, int n){
  for (int i = blockIdx.x*256 + threadIdx.x; i < n; i += gridDim.x*256) out[i] = f2bf(in[i]);
}
__global__ void k_prep_frag(const float* __restrict__ W, u16* __restrict__ out, int Nt, int K32, int K){
  int idx = blockIdx.x*256 + threadIdx.x;
  if (idx >= Nt*K32*64) return;
  int lane = idx & 63; int kk = (idx>>6) % K32; int tile = idx / (K32*64);
  const float* src = W + (size_t)(tile*16 + (lane&15))*K + kk*32 + ((lane>>4)<<3);
  u16* dst = out + (size_t)idx*8;
  #pragma unroll
  for (int j=0;j<8;++j) dst[j] = f2bf(src[j]);
}

// ---------------- gathers ----------------
__global__ void k_gather_src(const int* __restrict__ src, const float* __restrict__ emb, float* __restrict__ xs){
  const int n = S_SZ*B_SZ*E_SZ;
  for (int idx = blockIdx.x*blockDim.x + threadIdx.x; idx < n; idx += gridDim.x*blockDim.x){
    int e = idx & 255; int sb = idx >> 8; int b = sb & 15; int s = sb >> 4;
    int tok = src[b*S_SZ + s]; if (tok >= V_SZ) tok = UNK_TOK;
    xs[idx] = emb[tok*E_SZ + e];
  }
}
__global__ void k_gather_dec(const int* __restrict__ tgt, const float* __restrict__ emb, float* __restrict__ dx){
  const int n = (T_SZ-1)*B_SZ*E_SZ;
  for (int idx = blockIdx.x*blockDim.x + threadIdx.x; idx < n; idx += gridDim.x*blockDim.x){
    int e = idx & 255; int tb = idx >> 8; int b = tb & 15; int t = tb >> 4;
    int tok = tgt[b*T_SZ + t]; if (tok >= V_SZ) tok = UNK_TOK;
    dx[idx] = emb[tok*E_SZ + e];
  }
}
__global__ void k_gxscore(const float* __restrict__ dx, const float* __restrict__ gW, float* __restrict__ gx){
  int i = blockIdx.x*blockDim.x + threadIdx.x;
  if (i < (T_SZ-1)*B_SZ){
    const float* x = dx + i*E_SZ;
    const float* g = gW + 1024;
    float a = 0.f;
    for (int e=0;e<E_SZ;++e) a += x[e]*g[e];
    gx[i] = a;
  }
}

// ---------------- generic GEMM ----------------
__global__ __launch_bounds__(256) void k_gemm(const float* __restrict__ A, const float* __restrict__ WT,
                       const float* __restrict__ bias, float* __restrict__ C,
                       int M, int N, int K){
  __shared__ float As[32][36];
  int n = blockIdx.x*64 + (threadIdx.x & 63);
  int wv = threadIdx.x >> 6;
  int m0 = blockIdx.y*32;
  float acc[8];
  #pragma unroll
  for (int j=0;j<8;++j) acc[j]=0.f;
  for (int k0=0;k0<K;k0+=32){
    for (int e=threadIdx.x; e<1024; e+=256){
      int r = e>>5, c = e&31;
      int m = m0 + r;
      As[c][r] = (m<M)? A[m*K + k0 + c] : 0.f;
    }
    __syncthreads();
    #pragma unroll 8
    for (int k=0;k<32;++k){
      float w = WT[(k0+k)*N + n];
      const float* as = &As[k][wv*8];
      #pragma unroll
      for (int j=0;j<8;++j) acc[j] += as[j]*w;
    }
    __syncthreads();
  }
  float bv = bias[n];
  #pragma unroll
  for (int j=0;j<8;++j){
    int m = m0 + wv*8 + j;
    if (m<M) C[m*N + n] = acc[j] + bv;
  }
}

// ---------------- persistent bidirectional GRU encoder ----------------
__global__ __launch_bounds__(64) void k_enc_persist(
    const float* __restrict__ gi_f, const float* __restrict__ gi_b,
    const u16* __restrict__ Wbf_f, const u16* __restrict__ Wbf_b,
    const float* __restrict__ bhh_f, const float* __restrict__ bhh_b,
    float* __restrict__ enc_out, float* __restrict__ enc_hid,
    u16* __restrict__ h_bf, int* __restrict__ flags){
  __shared__ u16 wl[48*512];
  int lane = threadIdx.x;
  int d = blockIdx.x >> 5, slice = blockIdx.x & 31;
  int h0 = slice*16;
  const u16* Wb = d ? Wbf_b : Wbf_f;
  const float* gi = d ? gi_b : gi_f;
  const float* bhh = d ? bhh_b : bhh_f;
  int hl = h0 + (lane & 15);
  int quad = lane >> 4;
  int* myflag = flags + (d*32 + slice)*16;
  int* pollp  = flags + (d*32 + (lane & 31))*16;

  #pragma unroll 4
  for (int i=0;i<48;++i){
    int gg = i>>4, kk = i&15;
    const u16* src = Wb + ((size_t)(gg*512 + hl))*512 + kk*32 + quad*8;
    *(sv8*)&wl[i*512 + lane*8] = *(const sv8*)src;
  }
  __syncthreads();

  float b0 = bhh[hl], b1 = bhh[512+hl], b2 = bhh[1024+hl];
  float hold[4] = {0.f,0.f,0.f,0.f};

  #pragma unroll 1
  for (int t=0;t<S_SZ;++t){
    int pos = d ? (S_SZ-1-t) : t;
    const float* gp = gi + ((size_t)pos*16)*1536 + hl;
    float giv[12];
    #pragma unroll
    for (int gg=0;gg<3;++gg)
      #pragma unroll
      for (int r=0;r<4;++r)
        giv[gg*4+r] = gp[(quad*4 + r)*1536 + gg*512];

    if (t > 0){
      while (true){
        int v = __hip_atomic_load(pollp, __ATOMIC_RELAXED, __HIP_MEMORY_SCOPE_AGENT);
        unsigned long long m = __ballot(v >= t);
        if (m == ~0ull) break;
        __builtin_amdgcn_s_sleep(1);
      }
      __threadfence();
    }

    const u16* hb = h_bf + ((size_t)(t&1)*2 + d)*8192 + (lane&15)*512 + quad*8;
    f32x4 a0={0.f,0.f,0.f,0.f}, a1={0.f,0.f,0.f,0.f}, a2={0.f,0.f,0.f,0.f};
    #pragma unroll
    for (int kk=0;kk<16;++kk){
      sv8 a = *(const sv8*)(hb + kk*32);
      a0 = __builtin_amdgcn_mfma_f32_16x16x32_bf16(a, *(const sv8*)&wl[(kk)*512 + lane*8], a0, 0,0,0);
      a1 = __builtin_amdgcn_mfma_f32_16x16x32_bf16(a, *(const sv8*)&wl[(16+kk)*512 + lane*8], a1, 0,0,0);
      a2 = __builtin_amdgcn_mfma_f32_16x16x32_bf16(a, *(const sv8*)&wl[(32+kk)*512 + lane*8], a2, 0,0,0);
    }
    u16* hw = h_bf + ((size_t)((t+1)&1)*2 + d)*8192;
    #pragma unroll
    for (int r=0;r<4;++r){
      int b = quad*4 + r;
      float rg = sigf(giv[r]   + a0[r] + b0);
      float zg = sigf(giv[4+r] + a1[r] + b1);
      float ng = ftanh(giv[8+r] + rg*(a2[r] + b2));
      float hv = (1.f-zg)*ng + zg*hold[r];
      hold[r] = hv;
      enc_out[((size_t)b*S_SZ + pos)*1024 + d*512 + hl] = hv;
      hw[b*512 + hl] = f2bf(hv);
      if (t == S_SZ-1) enc_hid[b*1024 + d*512 + hl] = hv;
    }
    __threadfence();
    if (lane == 0)
      __hip_atomic_store(myflag, t+1, __ATOMIC_RELEASE, __HIP_MEMORY_SCOPE_AGENT);
  }
}

// ---------------- ctx_red GEMM (seeds h_dec0) ----------------
__global__ __launch_bounds__(256) void k_ctxred(const float* __restrict__ ctx, const float* __restrict__ rWT,
    const float* __restrict__ rb, float* __restrict__ h_cur, u16* __restrict__ u_bf){
  __shared__ float As[64][17];
  int lane = threadIdx.x & 63, wv = threadIdx.x >> 6;
  int n = blockIdx.x*64 + lane;
  float acc[4] = {0.f,0.f,0.f,0.f};
  for (int k0=0;k0<1024;k0+=64){
    for (int e=threadIdx.x; e<1024; e+=256){
      int r = e & 15, c = e >> 4;
      As[c][r] = ctx[r*1024 + k0 + c];
    }
    __syncthreads();
    #pragma unroll 8
    for (int k=0;k<64;++k){
      float w = rWT[(k0+k)*512 + n];
      #pragma unroll
      for (int j=0;j<4;++j) acc[j] += As[k][wv*4+j]*w;
    }
    __syncthreads();
  }
  float bv = rb[n];
  #pragma unroll
  for (int j=0;j<4;++j){
    int m = wv*4+j;
    float val = acc[j] + bv;
    h_cur[m*512 + n] = val;
    u_bf[m*1024 + n] = f2bf(val);
  }
}

// ---------------- fused persistent decoder: role-split + p2p flags ----------------
__global__ __launch_bounds__(256,2) void k_decoder(
    const float* __restrict__ dec_gi, u16* __restrict__ u_bf2,
    const u16* __restrict__ dfrag, const u16* __restrict__ sfrag,
    const float* __restrict__ dbhh, const float* __restrict__ abs_,
    const float* __restrict__ WhEnc, const float* __restrict__ aWc,
    const float* __restrict__ abc, const float* __restrict__ aV,
    const float* __restrict__ abv, const float* __restrict__ mask,
    const float* __restrict__ encR, const float* __restrict__ rb,
    const u16* __restrict__ fwB, const float* __restrict__ fb,
    const int* __restrict__ src_vecs, const int* __restrict__ tgt_vecs,
    const float* __restrict__ gW, const float* __restrict__ gb,
    const float* __restrict__ gx,
    float* __restrict__ hdec2, float* __restrict__ s_part,
    float* __restrict__ e_buf, float* __restrict__ attn2,
    float* __restrict__ cov, float* __restrict__ ctxp,
    u16* __restrict__ aFrag2, float* __restrict__ h_cur2,
    float* __restrict__ se_wave2, float* __restrict__ logit_tgt2,
    float* __restrict__ covloss2, float* __restrict__ loss_acc,
    int* __restrict__ flg){
  int tid = threadIdx.x;
  int lane = tid & 63;
  int wv = tid >> 6;
  int blk = blockIdx.x;
  int quad = lane >> 4;
  __shared__ __align__(16) char smem[65536];

  if (blk >= GG0){
    // ================= vocab group: 176 blocks / 704 waves =================
    int gb_ = blk - GG0;
    int gwv = gb_*4 + wv;
    int nT = (gwv < 309) ? 5 : 4;            // 3125 = 704*4 + 309
    float fbv[5];
    #pragma unroll
    for (int i=0;i<5;++i){
      int tl_ = gwv + 704*i;
      fbv[i] = (i < nT) ? fb[tl_*16 + (lane&15)] : 0.f;
    }
    u16* a_lds = (u16*)smem;                             // 32KB
    u16* mybuf = (u16*)(smem + 32768) + wv*4096;         // 4 bufs x 2KB per wave

    for (int t=0; t<T_SZ-1; ++t){
      int p = t&1;
      wait_ge(flg + FE2*16, 4, t+1);
      wait_ge(flg + FA*16, 8, t+1);
      // build A fragments in LDS (ctx_red lower-K from aFrag2; hdec upper-K from u_bf2)
      {
        const u16* ub = u_bf2 + (size_t)p*16384;
        const u16* af = aFrag2 + (size_t)p*8192;
        for (int f = tid; f < 2048; f += 256){
          sv8 fr;
          if (f < 1024){
            fr = *(const sv8*)(af + (size_t)f*8);
          } else {
            int kk = f>>6, l = f&63, r = l&15;
            int c8 = ((l>>4)<<3) + kk*32;
            fr = *(const sv8*)(ub + r*1024 + c8);
          }
          *(sv8*)(a_lds + (size_t)f*8) = fr;
        }
      }
      int tgtv[4];
      #pragma unroll
      for (int r=0;r<4;++r) tgtv[r] = tgt_vecs[(quad*4 + r)*T_SZ + t + 1];
      __syncthreads();   // drains vmcnt too -> clean counting for staged loads

      float es[4] = {0.f,0.f,0.f,0.f};
      float ltg[4] = {NEGV,NEGV,NEGV,NEGV};
      f32x4 acc = {0.f,0.f,0.f,0.f};
      int nC = nT*16;

      auto STAGE = [&](int c){
        int tile = gwv + 704*(c>>4);
        const u16* src = fwB + (size_t)tile*16384 + (size_t)(c&15)*1024 + lane*8;
        u16* dst = mybuf + (c&3)*1024;
        gld16(src, dst);
        gld16(src + 512, dst + 512);
      };
      STAGE(0); STAGE(1); STAGE(2); STAGE(3);

      #pragma unroll
      for (int i=0;i<5;++i) if (i < nT){
        if (i < nT-1){
          #pragma unroll
          for (int c2=0;c2<16;++c2){
            int c = i*16 + c2;
            asm volatile("s_waitcnt vmcnt(6)" ::: "memory");
            const u16* bp = mybuf + (c&3)*1024 + lane*8;
            int kk0 = c2*2;
            #pragma unroll
            for (int j=0;j<2;++j){
              sv8 af = *(const sv8*)(a_lds + (size_t)(kk0+j)*512 + lane*8);
              sv8 bfr = *(const sv8*)(bp + j*512);
              acc = __builtin_amdgcn_mfma_f32_16x16x32_bf16(af, bfr, acc, 0,0,0);
            }
            if (c2 == 15){
              int v = (gwv + 704*i)*16 + (lane&15);
              #pragma unroll
              for (int r=0;r<4;++r){
                float lg = acc[r] + fbv[i];
                if (v == tgtv[r]) ltg[r] = lg;
                es[r] += __expf(lg);
              }
              acc[0]=0.f; acc[1]=0.f; acc[2]=0.f; acc[3]=0.f;
            }
            STAGE(c+4);
          }
        } else {
          #pragma unroll
          for (int c2=0;c2<16;++c2){
            int c = i*16 + c2;
            int ahead = nC-1-c;
            if (ahead >= 3)      asm volatile("s_waitcnt vmcnt(6)" ::: "memory");
            else if (ahead == 2) asm volatile("s_waitcnt vmcnt(4)" ::: "memory");
            else if (ahead == 1) asm volatile("s_waitcnt vmcnt(2)" ::: "memory");
            else                 asm volatile("s_waitcnt vmcnt(0)" ::: "memory");
            const u16* bp = mybuf + (c&3)*1024 + lane*8;
            int kk0 = c2*2;
            #pragma unroll
            for (int j=0;j<2;++j){
              sv8 af = *(const sv8*)(a_lds + (size_t)(kk0+j)*512 + lane*8);
              sv8 bfr = *(const sv8*)(bp + j*512);
              acc = __builtin_amdgcn_mfma_f32_16x16x32_bf16(af, bfr, acc, 0,0,0);
            }
            if (c2 == 15){
              int v = (gwv + 704*i)*16 + (lane&15);
              #pragma unroll
              for (int r=0;r<4;++r){
                float lg = acc[r] + fbv[i];
                if (v == tgtv[r]) ltg[r] = lg;
                es[r] += __expf(lg);
              }
              acc[0]=0.f; acc[1]=0.f; acc[2]=0.f; acc[3]=0.f;
            }
            if (c+4 < nC) STAGE(c+4);
          }
        }
      }
      #pragma unroll
      for (int o=1;o<16;o<<=1){
        #pragma unroll
        for (int r=0;r<4;++r) es[r] += __shfl_xor(es[r], o);
      }
      if ((lane&15) == 0){
        #pragma unroll
        for (int r=0;r<4;++r) se_wave2[(size_t)p*12288 + (quad*4+r)*768 + gwv] = es[r];
      }
      #pragma unroll
      for (int r=0;r<4;++r)
        if (ltg[r] > -1e29f) logit_tgt2[p*16 + quad*4 + r] = ltg[r];
      post(flg + (FG + gb_)*16, t+1);
    }

  } else if (blk >= LOSS0){
    // ================= loss blocks 64..79 =================
    int b = blk - LOSS0;
    float loss_local = 0.f;
    float* red = (float*)smem;
    for (int t=0; t<T_SZ-1; ++t){
      wait_ge(flg + FG*16, NGG, t+1);
      int p = t&1;
      const float* sw = se_wave2 + (size_t)p*12288 + b*768;
      float a1 = 0.f;
      for (int i=tid; i<704; i+=256) a1 += sw[i];
      const float* hc = h_cur2 + (size_t)p*8192 + b*512;
      const float* hd = hdec2 + (size_t)p*8192 + b*512;
      float a2v = hc[tid]*gW[tid] + hd[tid]*gW[512+tid]
                + hc[256+tid]*gW[256+tid] + hd[256+tid]*gW[768+tid];
      int tg = tgt_vecs[b*T_SZ + t + 1];
      float a3 = 0.f;
      const float* at = attn2 + (size_t)p*6400 + b*400;
      if (src_vecs[b*S_SZ + tid] == tg) a3 += at[tid];
      if (tid < 144 && src_vecs[b*S_SZ + 256 + tid] == tg) a3 += at[256+tid];
      a1 = wsum(a1); a2v = wsum(a2v); a3 = wsum(a3);
      if (lane == 0){ red[wv] = a1; red[4+wv] = a2v; red[8+wv] = a3; }
      __syncthreads();
      if (tid == 0){
        float sume = red[0]+red[1]+red[2]+red[3];
        float dd   = red[4]+red[5]+red[6]+red[7];
        float ptr  = red[8]+red[9]+red[10]+red[11];
        float sc = dd + gx[t*16 + b] + gb[0];
        float pg = fminf(0.999f, fmaxf(0.001f, sigf(sc)));
        float tp = pg * (__expf(logit_tgt2[p*16 + b]) / sume) + (1.f-pg)*ptr;
        if (tg != 0) loss_local += -logf(tp + 1e-9f) + covloss2[p*16 + b];
      }
      post(flg + (FH + b)*16, t+1);
    }
    if (tid == 0) loss_acc[b] = loss_local;

  } else {
    // ================= chain blocks 0..63 =================
    float* sp  = (float*)smem;
    float* wcs = sp + 512;
    float* abS = sp + 1024;
    float* avS = sp + 1536;
    for (int i=tid; i<512; i+=256){ wcs[i] = aWc[i]; abS[i] = abc[i]; avS[i] = aV[i]; }
    __syncthreads();
    float abv0 = abv[0];

    for (int t=0; t<T_SZ-1; ++t){
      int p = t&1, pn = (t+1)&1;

      if (blk < 8){
        if (t > 0)  wait_ge(flg + FE2*16, 4, t);
        if (t >= 2){ wait_ge(flg + FG*16, NGG, t-1); wait_ge(flg + FH*16, NLOSS, t-1); }
        // ---- A: decoder GRU cell ----
        {
          int slice = blk*4 + wv;
          int h = slice*16 + (lane & 15);
          const u16* ubp = u_bf2 + (size_t)pn*16384;     // prev step's ctx_red (lower half)
          const u16* ap = ubp + (lane&15)*1024 + quad*8;
          f32x4 a0={0.f,0.f,0.f,0.f}, a1=a0, a2=a0;
          #pragma unroll
          for (int kk=0;kk<16;++kk){
            sv8 a = *(const sv8*)(ap + kk*32);
            a0 = __builtin_amdgcn_mfma_f32_16x16x32_bf16(a, *(const sv8*)(dfrag + ((size_t)(0*32+slice)*16 + kk)*512 + lane*8), a0, 0,0,0);
            a1 = __builtin_amdgcn_mfma_f32_16x16x32_bf16(a, *(const sv8*)(dfrag + ((size_t)(1*32+slice)*16 + kk)*512 + lane*8), a1, 0,0,0);
            a2 = __builtin_amdgcn_mfma_f32_16x16x32_bf16(a, *(const sv8*)(dfrag + ((size_t)(2*32+slice)*16 + kk)*512 + lane*8), a2, 0,0,0);
          }
          float b0 = dbhh[h], b1 = dbhh[512+h], b2 = dbhh[1024+h];
          const float* gi = dec_gi + (size_t)t*16*1536 + h;
          u16* ubw = u_bf2 + (size_t)p*16384;
          float* hd = hdec2 + (size_t)p*8192;
          #pragma unroll
          for (int r=0;r<4;++r){
            int b = quad*4 + r;
            const float* gp = gi + b*1536;
            float hlv = bf2f(ubp[b*1024 + h]);
            float rg = sigf(gp[0]    + a0[r] + b0);
            float zg = sigf(gp[512]  + a1[r] + b1);
            float ng = ftanh(gp[1024] + rg*(a2[r] + b2));
            float hv = (1.f-zg)*ng + zg*hlv;
            hd[b*512 + h] = hv;
            ubw[b*1024 + 512 + h] = f2bf(hv);
          }
        }
        post(flg + (FA + blk)*16, t+1);
        wait_ge(flg + FA*16, 8, t+1);
        // ---- B: s_part = hdec @ aWs.T + abs_ ----
        {
          int slice = blk*4 + wv;
          const u16* ap = u_bf2 + (size_t)p*16384 + (lane&15)*1024 + 512 + quad*8;
          const u16* bp = sfrag + (size_t)slice*16*512 + lane*8;
          f32x4 acc = {0.f,0.f,0.f,0.f};
          #pragma unroll
          for (int kk=0;kk<16;++kk){
            sv8 a = *(const sv8*)(ap + kk*32);
            acc = __builtin_amdgcn_mfma_f32_16x16x32_bf16(a, *(const sv8*)(bp + kk*512), acc, 0,0,0);
          }
          int h = slice*16 + (lane&15);
          float bv = abs_[h];
          #pragma unroll
          for (int r=0;r<4;++r) s_part[(quad*4+r)*512 + h] = acc[r] + bv;
        }
        post(flg + (FB + blk)*16, t+1);
      }

      // ---- C: attention scores (all 64 chain blocks; block serves batch blk>>2) ----
      wait_ge(flg + FB*16, 8, t+1);
      {
        int b = blk >> 2;
        int chunk = (blk&3)*4 + wv;
        for (int i=tid; i<512; i+=256) sp[i] = s_part[b*512 + i];
        __syncthreads();
        int s0 = chunk*25;
        for (int s = s0; s < s0+25; ++s){
          float cv = cov[b*400 + s];
          const float* wh = WhEnc + (size_t)(b*400 + s)*512;
          float a = 0.f;
          #pragma unroll
          for (int j=0;j<8;++j){
            int h2 = j*64 + lane;
            a += ftanh(wh[h2] + sp[h2] + cv*wcs[h2] + abS[h2]) * avS[h2];
          }
          a = wsum(a);
          if (lane == 0){
            float e = a + abv0;
            if (!(mask[b*400 + s] > 0.f)) e = NEGV;
            e_buf[b*400 + s] = e;
          }
        }
      }
      post(flg + (FC + blk)*16, t+1);

      // ---- D: softmax + coverage (blocks 0..15; block = batch) ----
      if (blk < 16){
        wait_ge(flg + (FC + 4*blk)*16, 4, t+1);
        if (t >= 2) wait_ge(flg + (FH + blk)*16, 1, t-1);
        int b = blk;
        float* red = (float*)smem + 2048;
        float e0 = e_buf[b*400 + tid];
        float e1 = (tid < 144) ? e_buf[b*400 + 256 + tid] : NEGV;
        float m = wmaxf(fmaxf(e0, e1));
        if (lane == 0) red[wv] = m;
        __syncthreads();
        float mx = fmaxf(fmaxf(red[0],red[1]), fmaxf(red[2],red[3]));
        float p0 = __expf(e0 - mx);
        float p1 = (tid < 144) ? __expf(e1 - mx) : 0.f;
        float sm = wsum(p0 + p1);
        if (lane == 0) red[4+wv] = sm;
        __syncthreads();
        float inv = 1.f/(red[4]+red[5]+red[6]+red[7]);
        float* an = attn2 + (size_t)p*6400 + b*400;
        float ml;
        {
          float a0v = p0*inv;
          an[tid] = a0v;
          float cn = cov[b*400 + tid] + a0v;
          cov[b*400 + tid] = cn;
          ml = fminf(a0v, cn);
        }
        if (tid < 144){
          float a1v = p1*inv;
          an[256+tid] = a1v;
          float cn = cov[b*400 + 256 + tid] + a1v;
          cov[b*400 + 256 + tid] = cn;
          ml += fminf(a1v, cn);
        }
        float cs = wsum(ml);
        if (lane == 0) red[8+wv] = cs;
        __syncthreads();
        if (tid == 0) covloss2[p*16 + b] = red[8]+red[9]+red[10]+red[11];
        post(flg + (FD + blk)*16, t+1);
      }

      // ---- E: ctx_red partials = attn @ encR ----
      {
        int b = blk >> 2;
        wait_ge(flg + (FD + b)*16, 1, t+1);
        int local = (blk&3)*4 + wv;
        int nch = local >> 1, sh = local & 1;
        int n0 = nch*64, s0 = sh*200;
        const float* at2 = attn2 + (size_t)p*6400 + b*400 + s0;
        const float* er = encR + ((size_t)(b*400 + s0))*512 + n0 + lane;
        float acc2 = 0.f;
        #pragma unroll 5
        for (int s=0;s<200;++s) acc2 += at2[s] * er[(size_t)s*512];
        ctxp[(sh*16 + b)*512 + n0 + lane] = acc2;
      }
      post(flg + (FE + blk)*16, t+1);

      // ---- E2: combine -> ctx_red (blocks 0..3) ----
      if (blk < 4){
        wait_ge(flg + FE*16, SGB, t+1);
        int f = blk*256 + tid;
        int kk = f >> 6, l = f & 63, r = l & 15;
        int c8 = ((l >> 4) << 3) + kk*32;
        float v[8];
        #pragma unroll
        for (int j=0;j<8;++j)
          v[j] = rb[c8+j] + ctxp[r*512 + c8 + j] + ctxp[(16+r)*512 + c8 + j];
        sv8 fr;
        #pragma unroll
        for (int j=0;j<8;++j) fr[j] = (short)f2bf(v[j]);
        *(sv8*)(aFrag2 + (size_t)p*8192 + (size_t)f*8) = fr;
        *(sv8*)(u_bf2 + (size_t)p*16384 + r*1024 + c8) = fr;
        f32x4 v0 = {v[0],v[1],v[2],v[3]};
        f32x4 v1 = {v[4],v[5],v[6],v[7]};
        *(f32x4*)(h_cur2 + (size_t)p*8192 + r*512 + c8) = v0;
        *(f32x4*)(h_cur2 + (size_t)p*8192 + r*512 + c8 + 4) = v1;
        post(flg + (FE2 + blk)*16, t+1);
      }
    }
  }
}

// ---------------- output ----------------
__global__ void k_out(const float* __restrict__ loss_acc, const int* __restrict__ tgt_vecs, float* __restrict__ out){
  __shared__ float s[16];
  int tid = threadIdx.x;
  if (tid < 16){
    int c = 0;
    for (int t=0;t<T_SZ;++t) c += (tgt_vecs[tid*T_SZ + t] != 0) ? 1 : 0;
    s[tid] = loss_acc[tid] / (float)(c - 1);
  }
  __syncthreads();
  if (tid == 0){
    float a = 0.f;
    for (int b=0;b<16;++b) a += s[b];
    out[0] = a / 16.f;
  }
}

extern "C" void kernel_launch(void* const* d_in, const int* in_sizes, int n_in,
                              void* d_out, int out_size, void* d_ws, size_t ws_size,
                              hipStream_t stream){
  (void)in_sizes; (void)n_in; (void)out_size; (void)ws_size;
  const int*   src_vecs = (const int*)d_in[0];
  const float* src_mask = (const float*)d_in[1];
  const int*   tgt_vecs = (const int*)d_in[2];
  const float* enc_embed= (const float*)d_in[4];
  const float* dec_embed= (const float*)d_in[5];
  const float* eWih_f = (const float*)d_in[6];
  const float* eWhh_f = (const float*)d_in[7];
  const float* ebih_f = (const float*)d_in[8];
  const float* ebhh_f = (const float*)d_in[9];
  const float* eWih_b = (const float*)d_in[10];
  const float* eWhh_b = (const float*)d_in[11];
  const float* ebih_b = (const float*)d_in[12];
  const float* ebhh_b = (const float*)d_in[13];
  const float* dWih = (const float*)d_in[14];
  const float* dWhh = (const float*)d_in[15];
  const float* dbih = (const float*)d_in[16];
  const float* dbhh = (const float*)d_in[17];
  const float* aWh  = (const float*)d_in[18];
  const float* abh  = (const float*)d_in[19];
  const float* aWs  = (const float*)d_in[20];
  const float* abs_ = (const float*)d_in[21];
  const float* aWc  = (const float*)d_in[22];
  const float* abc  = (const float*)d_in[23];
  const float* aV   = (const float*)d_in[24];
  const float* abv  = (const float*)d_in[25];
  const float* rW   = (const float*)d_in[26];
  const float* rb   = (const float*)d_in[27];
  const float* gW   = (const float*)d_in[28];
  const float* gb   = (const float*)d_in[29];
  const float* fW   = (const float*)d_in[30];
  const float* fb   = (const float*)d_in[31];
  float* out = (float*)d_out;

  char* p = (char*)d_ws;
  auto alloc = [&](size_t n)->char*{ char* r = p; p += (n + 255) & ~(size_t)255; return r; };
  float* xs      = (float*)alloc((size_t)S_SZ*B_SZ*E_SZ*4);
  float* gi_f    = (float*)alloc((size_t)S_SZ*B_SZ*1536*4);
  float* gi_b    = (float*)alloc((size_t)S_SZ*B_SZ*1536*4);
  float* enc_out = (float*)alloc((size_t)B_SZ*S_SZ*1024*4);
  float* WhEnc   = (float*)alloc((size_t)B_SZ*S_SZ*512*4);
  float* dec_x   = (float*)alloc((size_t)(T_SZ-1)*B_SZ*E_SZ*4);
  float* dec_gi  = (float*)alloc((size_t)(T_SZ-1)*B_SZ*1536*4);
  float* gx      = (float*)alloc((size_t)(T_SZ-1)*B_SZ*4);
  float* eWihT_f = (float*)alloc((size_t)256*1536*4);
  float* eWihT_b = (float*)alloc((size_t)256*1536*4);
  float* dWihT   = (float*)alloc((size_t)256*1536*4);
  float* aWhT    = (float*)alloc((size_t)1024*512*4);
  float* rWT     = (float*)alloc((size_t)1024*512*4);
  u16* Wbf_f     = (u16*)alloc((size_t)1536*512*2);
  u16* Wbf_b     = (u16*)alloc((size_t)1536*512*2);
  u16* dfrag     = (u16*)alloc((size_t)96*16*512*2);
  u16* sfrag     = (u16*)alloc((size_t)32*16*512*2);
  u16* fwB       = (u16*)alloc((size_t)3125*16384*2);
  u16* h_bf      = (u16*)alloc((size_t)2*2*16*512*2);
  int* flags     = (int*)alloc(64*16*4);
  float* enc_hid = (float*)alloc((size_t)B_SZ*1024*4);
  float* s_part  = (float*)alloc((size_t)B_SZ*H_SZ*4);
  float* e_buf   = (float*)alloc((size_t)B_SZ*S_SZ*4);
  float* cov     = (float*)alloc((size_t)B_SZ*S_SZ*4);
  float* loss_acc= (float*)alloc(64*4);
  // fused decoder buffers (parity double-buffered)
  float* encR    = (float*)alloc((size_t)B_SZ*S_SZ*512*4);
  u16* u_bf2     = (u16*)alloc((size_t)2*16*1024*2);
  u16* aFrag2    = (u16*)alloc((size_t)2*1024*8*2);
  float* attn2   = (float*)alloc((size_t)2*B_SZ*S_SZ*4);
  float* h_cur2  = (float*)alloc((size_t)2*B_SZ*H_SZ*4);
  float* hdec2   = (float*)alloc((size_t)2*B_SZ*H_SZ*4);
  float* ctxp    = (float*)alloc((size_t)2*16*512*4);
  float* se_wave2= (float*)alloc((size_t)2*16*768*4);
  float* logit_tgt2 = (float*)alloc(2*16*4);
  float* covloss2   = (float*)alloc(2*16*4);
  int* dflags    = (int*)alloc((size_t)512*16*4);
  float* zeros512= (float*)alloc(512*4);

  dim3 tb(32,8);
  k_init<<<128,256,0,stream>>>((u32*)h_bf, flags, cov, loss_acc, dflags, zeros512);
  k_transpose<<<dim3(8,48),tb,0,stream>>>(eWih_f, eWihT_f, 1536, 256);
  k_transpose<<<dim3(8,48),tb,0,stream>>>(eWih_b, eWihT_b, 1536, 256);
  k_transpose<<<dim3(8,48),tb,0,stream>>>(dWih, dWihT, 1536, 256);
  k_transpose<<<dim3(32,16),tb,0,stream>>>(aWh, aWhT, 512, 1024);
  k_transpose<<<dim3(32,16),tb,0,stream>>>(rW, rWT, 512, 1024);
  k_f2bf<<<3072,256,0,stream>>>(eWhh_f, Wbf_f, 1536*512);
  k_f2bf<<<3072,256,0,stream>>>(eWhh_b, Wbf_b, 1536*512);
  k_prep_frag<<<384,256,0,stream>>>(dWhh, dfrag, 96, 16, 512);
  k_prep_frag<<<128,256,0,stream>>>(aWs, sfrag, 32, 16, 512);
  k_prep_frag<<<25000,256,0,stream>>>(fW, fwB, 3125, 32, 1024);
  k_gather_src<<<1024,256,0,stream>>>(src_vecs, enc_embed, xs);
  k_gather_dec<<<512,256,0,stream>>>(tgt_vecs, dec_embed, dec_x);
  k_gxscore<<<7,256,0,stream>>>(dec_x, gW, gx);
  k_gemm<<<dim3(24,200),256,0,stream>>>(xs, eWihT_f, ebih_f, gi_f, 6400,1536,256);
  k_gemm<<<dim3(24,200),256,0,stream>>>(xs, eWihT_b, ebih_b, gi_b, 6400,1536,256);
  k_gemm<<<dim3(24,50),256,0,stream>>>(dec_x, dWihT, dbih, dec_gi, 1584,1536,256);

  k_enc_persist<<<64,64,0,stream>>>(gi_f, gi_b, Wbf_f, Wbf_b, ebhh_f, ebhh_b,
                                    enc_out, enc_hid, h_bf, flags);

  // h_dec0 -> seeds u_bf parity-1 lower half (read by A at t=0)
  k_ctxred<<<8,256,0,stream>>>(enc_hid, rWT, rb, h_cur2, u_bf2 + 16384);
  k_gemm<<<dim3(8,200),256,0,stream>>>(enc_out, aWhT, abh, WhEnc, 6400,512,1024);
  k_gemm<<<dim3(8,200),256,0,stream>>>(enc_out, rWT, zeros512, encR, 6400,512,1024);

  k_decoder<<<NB,256,0,stream>>>(dec_gi, u_bf2, dfrag, sfrag, dbhh, abs_,
                                 WhEnc, aWc, abc, aV, abv, src_mask,
                                 encR, rb, fwB, fb, src_vecs, tgt_vecs,
                                 gW, gb, gx,
                                 hdec2, s_part, e_buf, attn2, cov, ctxp,
                                 aFrag2, h_cur2, se_wave2, logit_tgt2, covloss2,
                                 loss_acc, dflags);

  k_out<<<1,64,0,stream>>>(loss_acc, tgt_vecs, out);
}